// Round 1
// baseline (466.030 us; speedup 1.0000x reference)
//
#include <hip/hip_runtime.h>
#include <hip/hip_bf16.h>

// Problem constants (from the reference):
// B=1024, M=4 segments, L=100 tokens, D=512, V=50000, H=512, DEC_HID=128
constexpr int NB   = 1024;
constexpr int NSEG = 4;
constexpr int LSEQ = 100;
constexpr int ND   = 512;
constexpr int NH   = 512;
constexpr int NDEC = 128;

// ---------------------------------------------------------------------------
// Pooling: for each (b, m) compute masked average of embed_table[tok] over
// the 100 tokens (tok != 0). Writes x_pool[(b*4+m)*512 + d]; the m==1 result
// is also x_future -> written straight into d_out's second region.
// 128 threads/block, each owns 4 consecutive floats (float4) of the 512-dim.
// ---------------------------------------------------------------------------
__global__ __launch_bounds__(128)
void pool_kernel(const int* __restrict__ toks, const float* __restrict__ table,
                 float* __restrict__ xpool, float* __restrict__ xfut)
{
    const int bm = blockIdx.x;      // b*4 + m
    const int m  = bm & 3;
    __shared__ int stok[LSEQ];
    const int tid = threadIdx.x;
    if (tid < LSEQ) stok[tid] = toks[(size_t)bm * LSEQ + tid];
    __syncthreads();

    const int d = tid * 4;
    float4 acc = {0.f, 0.f, 0.f, 0.f};
    int cnt = 0;
    for (int l = 0; l < LSEQ; ++l) {
        const int t = stok[l];           // uniform across block
        if (t != 0) {
            ++cnt;
            const float4 e = *(const float4*)&table[(size_t)t * ND + d];
            acc.x += e.x; acc.y += e.y; acc.z += e.z; acc.w += e.w;
        }
    }
    const float inv = 1.0f / (float)(cnt > 0 ? cnt : 1);
    acc.x *= inv; acc.y *= inv; acc.z *= inv; acc.w *= inv;

    *(float4*)&xpool[(size_t)bm * ND + d] = acc;
    if (m == 1)
        *(float4*)&xfut[(size_t)(bm >> 2) * ND + d] = acc;
}

// ---------------------------------------------------------------------------
// Fused fp32 GEMM: C = act( [A0*rowscale, A1] @ [W0, W1]^T + b0 + b1 )
//   A0: M x K0 (row stride lda0), optional per-row scale (scale[row*sstride])
//   A1: M x K1 (row stride lda1), may be null (K1 == 0)
//   W0: N x K0 row-major;  W1: N x K1 row-major
//   b1 may be null.  RELU template flag selects activation.
// 64x64 tile, BK=16, 256 threads, 4x4 per-thread microtile.
// All dims here are multiples of the tile sizes (M=1024, N in {512,128},
// K in {512,128,1024}) -> no bounds checks.
// ---------------------------------------------------------------------------
template<bool RELU>
__global__ __launch_bounds__(256)
void gemm_bias_act(const float* __restrict__ A0, int lda0,
                   const float* __restrict__ scale, int sstride,
                   const float* __restrict__ A1, int lda1,
                   const float* __restrict__ W0, const float* __restrict__ W1,
                   const float* __restrict__ b0, const float* __restrict__ b1,
                   float* __restrict__ C, int ldc,
                   int K0, int K1)
{
    constexpr int BM = 64, BN = 64, BK = 16;
    // +4 pad keeps rows 16B-aligned (68*4 = 272 = 16*17) and staggers banks.
    __shared__ float As[BK][BM + 4];
    __shared__ float Ws[BK][BN + 4];

    const int tid  = threadIdx.x;
    const int tx   = tid & 15;       // output col group
    const int ty   = tid >> 4;       // output row group
    const int row0 = blockIdx.y * BM;
    const int col0 = blockIdx.x * BN;

    // loader coords: each thread loads one float4 of A and one of W per tile
    const int lm = tid >> 2;          // 0..63 (row within tile)
    const int lk = (tid & 3) * 4;     // 0,4,8,12 (col within BK)

    float acc[4][4] = {};
    const int Ktot = K0 + K1;

    for (int kt = 0; kt < Ktot; kt += BK) {
        const bool first = (kt < K0);
        const float* Asrc = first ? A0 : A1;
        const int    lda  = first ? lda0 : lda1;
        const float* Wsrc = first ? W0 : W1;
        const int    ldw  = first ? K0 : K1;
        const int    kloc = first ? kt : kt - K0;

        float4 av = *(const float4*)&Asrc[(size_t)(row0 + lm) * lda + kloc + lk];
        if (first && scale) {
            const float sc = scale[(size_t)(row0 + lm) * sstride];
            av.x *= sc; av.y *= sc; av.z *= sc; av.w *= sc;
        }
        const float4 wv = *(const float4*)&Wsrc[(size_t)(col0 + lm) * ldw + kloc + lk];

        As[lk + 0][lm] = av.x; As[lk + 1][lm] = av.y;
        As[lk + 2][lm] = av.z; As[lk + 3][lm] = av.w;
        Ws[lk + 0][lm] = wv.x; Ws[lk + 1][lm] = wv.y;
        Ws[lk + 2][lm] = wv.z; Ws[lk + 3][lm] = wv.w;
        __syncthreads();

        #pragma unroll
        for (int kk = 0; kk < BK; ++kk) {
            const float4 a = *(const float4*)&As[kk][ty * 4];
            const float4 w = *(const float4*)&Ws[kk][tx * 4];
            const float aa[4] = {a.x, a.y, a.z, a.w};
            const float ww[4] = {w.x, w.y, w.z, w.w};
            #pragma unroll
            for (int i = 0; i < 4; ++i)
                #pragma unroll
                for (int j = 0; j < 4; ++j)
                    acc[i][j] = fmaf(aa[i], ww[j], acc[i][j]);
        }
        __syncthreads();
    }

    #pragma unroll
    for (int j = 0; j < 4; ++j) {
        const int n = col0 + tx * 4 + j;
        const float bb = b0[n] + (b1 ? b1[n] : 0.0f);
        #pragma unroll
        for (int i = 0; i < 4; ++i) {
            float v = acc[i][j] + bb;
            if (RELU) v = fmaxf(v, 0.0f);
            C[(size_t)(row0 + ty * 4 + i) * ldc + n] = v;
        }
    }
}

extern "C" void kernel_launch(void* const* d_in, const int* in_sizes, int n_in,
                              void* d_out, int out_size, void* d_ws, size_t ws_size,
                              hipStream_t stream)
{
    const int*   inputs = (const int*)  d_in[0];
    const float* masks  = (const float*)d_in[1];
    const float* embed  = (const float*)d_in[2];
    const float* w_ih0  = (const float*)d_in[3];
    const float* w_hh0  = (const float*)d_in[4];
    const float* b_ih0  = (const float*)d_in[5];
    const float* b_hh0  = (const float*)d_in[6];
    const float* w_ih1  = (const float*)d_in[7];
    const float* w_hh1  = (const float*)d_in[8];
    const float* b_ih1  = (const float*)d_in[9];
    const float* b_hh1  = (const float*)d_in[10];
    const float* w_d1   = (const float*)d_in[11];
    const float* b_d1   = (const float*)d_in[12];
    const float* w_d2   = (const float*)d_in[13];
    const float* b_d2   = (const float*)d_in[14];

    float* out    = (float*)d_out;
    float* xf_hat = out;                          // (B, D)
    float* xf     = out + (size_t)NB * ND;        // (B, D)
    float* lasth  = out + 2 * (size_t)NB * ND;    // (B, H)

    // workspace layout (floats): x_pool[B*4*D] | h0a | h0b | h1a | h1b | dec1
    float* xpool = (float*)d_ws;
    float* h0a   = xpool + (size_t)NB * NSEG * ND;
    float* h0b   = h0a + (size_t)NB * NH;
    float* h1a   = h0b + (size_t)NB * NH;
    float* h1b   = h1a + (size_t)NB * NH;
    float* dec1  = h1b + (size_t)NB * NH;

    // 1) pooling (also writes x_future into d_out)
    pool_kernel<<<NB * NSEG, 128, 0, stream>>>(inputs, embed, xpool, xf);

    const dim3 blk(256);
    const dim3 gH (NH   / 64, NB / 64);   // N=512
    const dim3 gD1(NDEC / 64, NB / 64);   // N=128
    const dim3 gD2(ND   / 64, NB / 64);   // N=512

    // 2) RNN: scan order past = [3, 2, 0]; h starts at zero (K1=0 on step 0)
    // step 0 (seg 3)
    gemm_bias_act<true><<<gH, blk, 0, stream>>>(
        xpool + 3 * ND, NSEG * ND, masks + 3, NSEG, nullptr, 0,
        w_ih0, nullptr, b_ih0, b_hh0, h0a, NH, ND, 0);
    gemm_bias_act<true><<<gH, blk, 0, stream>>>(
        h0a, NH, nullptr, 0, nullptr, 0,
        w_ih1, nullptr, b_ih1, b_hh1, h1a, NH, NH, 0);
    // step 1 (seg 2)
    gemm_bias_act<true><<<gH, blk, 0, stream>>>(
        xpool + 2 * ND, NSEG * ND, masks + 2, NSEG, h0a, NH,
        w_ih0, w_hh0, b_ih0, b_hh0, h0b, NH, ND, NH);
    gemm_bias_act<true><<<gH, blk, 0, stream>>>(
        h0b, NH, nullptr, 0, h1a, NH,
        w_ih1, w_hh1, b_ih1, b_hh1, h1b, NH, NH, NH);
    // step 2 (seg 0)
    gemm_bias_act<true><<<gH, blk, 0, stream>>>(
        xpool + 0 * ND, NSEG * ND, masks + 0, NSEG, h0b, NH,
        w_ih0, w_hh0, b_ih0, b_hh0, h0a, NH, ND, NH);
    gemm_bias_act<true><<<gH, blk, 0, stream>>>(
        h0a, NH, nullptr, 0, h1b, NH,
        w_ih1, w_hh1, b_ih1, b_hh1, lasth, NH, NH, NH);   // last_h -> d_out

    // 3) decoder
    gemm_bias_act<true><<<gD1, blk, 0, stream>>>(
        lasth, NH, nullptr, 0, nullptr, 0,
        w_d1, nullptr, b_d1, nullptr, dec1, NDEC, NH, 0);
    gemm_bias_act<false><<<gD2, blk, 0, stream>>>(
        dec1, NDEC, nullptr, 0, nullptr, 0,
        w_d2, nullptr, b_d2, nullptr, xf_hat, ND, NDEC, 0);
}

// Round 2
// 237.456 us; speedup vs baseline: 1.9626x; 1.9626x over previous
//
#include <hip/hip_runtime.h>
#include <hip/hip_bf16.h>

// B=1024, M=4 segments, L=100 tokens, D=512, V=50000, H=512, DEC_HID=128
constexpr int NB   = 1024;
constexpr int NSEG = 4;
constexpr int LSEQ = 100;
constexpr int ND   = 512;
constexpr int NH   = 512;
constexpr int NDEC = 128;

typedef __attribute__((ext_vector_type(8))) short bf16x8;
typedef __attribute__((ext_vector_type(4))) float f32x4;

__device__ __forceinline__ ushort f2bf(float f) {
    union { float f; unsigned u; } v; v.f = f;
    unsigned r = (v.u + 0x7fffu + ((v.u >> 16) & 1u)) >> 16;   // RNE
    return (ushort)r;
}

// global -> LDS direct copy, 16 B per lane. LDS dest is wave-uniform base;
// lane i lands at base + i*16. Global src is per-lane (pre-swizzled).
#define GLOAD_LDS16(gp, lp)                                                     \
    __builtin_amdgcn_global_load_lds(                                           \
        (const __attribute__((address_space(1))) unsigned int*)(gp),            \
        (__attribute__((address_space(3))) unsigned int*)(lp), 16, 0, 0)

// ---------------------------------------------------------------------------
// Pooling: masked avg of embed rows over 100 tokens per (b,m).
// Emits bf16 xpool (pre-multiplied by masks[b,m]) for RNN input; the m==1
// result goes unscaled as fp32 x_future into d_out.
// ---------------------------------------------------------------------------
__global__ __launch_bounds__(128)
void pool_kernel(const int* __restrict__ toks, const float* __restrict__ table,
                 const float* __restrict__ masks,
                 ushort* __restrict__ xpool, float* __restrict__ xfut)
{
    const int bm = blockIdx.x;      // b*4 + m
    const int m  = bm & 3;
    __shared__ int stok[LSEQ];
    const int tid = threadIdx.x;
    if (tid < LSEQ) stok[tid] = toks[(size_t)bm * LSEQ + tid];
    __syncthreads();

    const int d = tid * 4;
    float4 acc = {0.f, 0.f, 0.f, 0.f};
    int cnt = 0;
    for (int l = 0; l < LSEQ; ++l) {
        const int t = stok[l];           // uniform across block
        if (t != 0) {
            ++cnt;
            const float4 e = *(const float4*)&table[(size_t)t * ND + d];
            acc.x += e.x; acc.y += e.y; acc.z += e.z; acc.w += e.w;
        }
    }
    const float inv = 1.0f / (float)(cnt > 0 ? cnt : 1);
    acc.x *= inv; acc.y *= inv; acc.z *= inv; acc.w *= inv;

    if (m == 1) {
        *(float4*)&xfut[(size_t)(bm >> 2) * ND + d] = acc;
    } else {
        const float sc = masks[bm];      // exactly 0.0 or 1.0
        ushort4 o;
        o.x = f2bf(acc.x * sc); o.y = f2bf(acc.y * sc);
        o.z = f2bf(acc.z * sc); o.w = f2bf(acc.w * sc);
        *(ushort4*)&xpool[(size_t)bm * ND + d] = o;
    }
}

// ---------------------------------------------------------------------------
// Convert the 6 weight matrices to bf16 and pre-sum the RNN bias pairs.
// ---------------------------------------------------------------------------
__global__ __launch_bounds__(256)
void convert_weights(const float* __restrict__ w_ih0, const float* __restrict__ w_hh0,
                     const float* __restrict__ w_ih1, const float* __restrict__ w_hh1,
                     const float* __restrict__ w_d1,  const float* __restrict__ w_d2,
                     const float* __restrict__ b_ih0, const float* __restrict__ b_hh0,
                     const float* __restrict__ b_ih1, const float* __restrict__ b_hh1,
                     ushort* __restrict__ wbf, float* __restrict__ bsum0,
                     float* __restrict__ bsum1)
{
    constexpr int N0 = 512 * 512;           // 262144
    constexpr int ND2 = 128 * 512;          // 65536
    constexpr int TOT = 4 * N0 + 2 * ND2 + 1024;
    for (int i = blockIdx.x * blockDim.x + threadIdx.x; i < TOT;
         i += gridDim.x * blockDim.x) {
        if (i < 4 * N0) {
            const float* src = (i < N0) ? w_ih0 : (i < 2*N0) ? w_hh0
                             : (i < 3*N0) ? w_ih1 : w_hh1;
            wbf[i] = f2bf(src[i & (N0 - 1)]);
        } else if (i < 4 * N0 + ND2) {
            wbf[i] = f2bf(w_d1[i - 4 * N0]);
        } else if (i < 4 * N0 + 2 * ND2) {
            wbf[i] = f2bf(w_d2[i - 4 * N0 - ND2]);
        } else {
            const int j = i - (4 * N0 + 2 * ND2);
            if (j < 512) bsum0[j] = b_ih0[j] + b_hh0[j];
            else         bsum1[j - 512] = b_ih1[j - 512] + b_hh1[j - 512];
        }
    }
}

// ---------------------------------------------------------------------------
// bf16 MFMA GEMM: C = act( [A0, A1] @ [W0, W1]^T + bias )
// A*: M x K* bf16 row-major (row strides lda*); W*: N x K* bf16 row-major.
// 64x64 tile, BK=32, 256 threads = 4 waves, each wave one 32x32 quadrant
// (2x2 of 16x16x32 fragments). Staging via global_load_lds(16B) with
// per-lane fragment-ordered global addresses -> LDS is lane-linear,
// ds_read_b128 conflict-free. All dims multiples of tile sizes.
// ---------------------------------------------------------------------------
template<bool RELU, bool WF32, bool WBF>
__global__ __launch_bounds__(256)
void mfma_gemm(const ushort* __restrict__ A0, int lda0,
               const ushort* __restrict__ A1, int lda1,
               const ushort* __restrict__ W0, int ldw0,
               const ushort* __restrict__ W1, int ldw1,
               const float* __restrict__ bias,
               float* __restrict__ Cf, ushort* __restrict__ Cb, int ldc,
               int K0, int K1)
{
    __shared__ ushort As[4 * 512];   // 4 fragments x (64 lanes x 8 bf16)
    __shared__ ushort Ws[4 * 512];

    const int tid  = threadIdx.x;
    const int lane = tid & 63;
    const int wid  = tid >> 6;        // 0..3
    const int l15  = lane & 15;       // fragment row / col
    const int slot = lane >> 4;       // k-chunk (8 bf16 each)
    const int wr   = wid >> 1;        // wave quadrant row (0/1)
    const int wc   = wid & 1;         // wave quadrant col (0/1)
    const int row0 = blockIdx.y * 64;
    const int col0 = blockIdx.x * 64;

    f32x4 acc[2][2] = {};

    const ushort* Ab[2] = {A0, A1};
    const ushort* Wb[2] = {W0, W1};
    const int ldas[2] = {lda0, lda1};
    const int ldws[2] = {ldw0, ldw1};
    const int Ks[2]   = {K0, K1};

    for (int ph = 0; ph < 2; ++ph) {
        const int K = Ks[ph];
        if (K == 0) continue;
        // per-lane global src: row (l15) of this wave's fragment, k-chunk slot
        const ushort* ga = Ab[ph] + (size_t)(row0 + wid * 16 + l15) * ldas[ph] + slot * 8;
        const ushort* gw = Wb[ph] + (size_t)(col0 + wid * 16 + l15) * ldws[ph] + slot * 8;
        for (int kt = 0; kt < K; kt += 32) {
            GLOAD_LDS16(ga + kt, &As[wid * 512]);   // wave wid stages frag wid
            GLOAD_LDS16(gw + kt, &Ws[wid * 512]);
            __syncthreads();                         // drains vmcnt
            const bf16x8 a0 = *(const bf16x8*)&As[(wr * 2 + 0) * 512 + lane * 8];
            const bf16x8 a1 = *(const bf16x8*)&As[(wr * 2 + 1) * 512 + lane * 8];
            const bf16x8 b0 = *(const bf16x8*)&Ws[(wc * 2 + 0) * 512 + lane * 8];
            const bf16x8 b1 = *(const bf16x8*)&Ws[(wc * 2 + 1) * 512 + lane * 8];
            acc[0][0] = __builtin_amdgcn_mfma_f32_16x16x32_bf16(a0, b0, acc[0][0], 0, 0, 0);
            acc[0][1] = __builtin_amdgcn_mfma_f32_16x16x32_bf16(a0, b1, acc[0][1], 0, 0, 0);
            acc[1][0] = __builtin_amdgcn_mfma_f32_16x16x32_bf16(a1, b0, acc[1][0], 0, 0, 0);
            acc[1][1] = __builtin_amdgcn_mfma_f32_16x16x32_bf16(a1, b1, acc[1][1], 0, 0, 0);
            __syncthreads();
        }
    }

    // epilogue: D[(lane>>4)*4 + r][lane&15] per fragment
    #pragma unroll
    for (int fi = 0; fi < 2; ++fi)
        #pragma unroll
        for (int fj = 0; fj < 2; ++fj) {
            const int r0 = row0 + wr * 32 + fi * 16 + slot * 4;
            const int c  = col0 + wc * 32 + fj * 16 + l15;
            const float bb = bias ? bias[c] : 0.0f;
            #pragma unroll
            for (int r = 0; r < 4; ++r) {
                float v = acc[fi][fj][r] + bb;
                if (RELU) v = fmaxf(v, 0.0f);
                if (WF32) Cf[(size_t)(r0 + r) * ldc + c] = v;
                if (WBF)  Cb[(size_t)(r0 + r) * ldc + c] = f2bf(v);
            }
        }
}

extern "C" void kernel_launch(void* const* d_in, const int* in_sizes, int n_in,
                              void* d_out, int out_size, void* d_ws, size_t ws_size,
                              hipStream_t stream)
{
    (void)in_sizes; (void)n_in; (void)out_size; (void)ws_size;
    const int*   inputs = (const int*)  d_in[0];
    const float* masks  = (const float*)d_in[1];
    const float* embed  = (const float*)d_in[2];
    const float* w_ih0  = (const float*)d_in[3];
    const float* w_hh0  = (const float*)d_in[4];
    const float* b_ih0  = (const float*)d_in[5];
    const float* b_hh0  = (const float*)d_in[6];
    const float* w_ih1  = (const float*)d_in[7];
    const float* w_hh1  = (const float*)d_in[8];
    const float* b_ih1  = (const float*)d_in[9];
    const float* b_hh1  = (const float*)d_in[10];
    const float* w_d1   = (const float*)d_in[11];
    const float* b_d1   = (const float*)d_in[12];
    const float* w_d2   = (const float*)d_in[13];
    const float* b_d2   = (const float*)d_in[14];

    float* out    = (float*)d_out;
    float* xf_hat = out;                          // (B, D)
    float* xf     = out + (size_t)NB * ND;        // (B, D)
    float* lasth  = out + 2 * (size_t)NB * ND;    // (B, H)

    // workspace layout
    char* ws = (char*)d_ws;
    ushort* wbf   = (ushort*)ws;                 ws += (size_t)1179648 * 2;  // 6 weights bf16
    float*  bsum0 = (float*)ws;                  ws += 512 * 4;
    float*  bsum1 = (float*)ws;                  ws += 512 * 4;
    ushort* xpool = (ushort*)ws;                 ws += (size_t)NB * NSEG * ND * 2;
    ushort* h0a   = (ushort*)ws;                 ws += (size_t)NB * NH * 2;
    ushort* h0b   = (ushort*)ws;                 ws += (size_t)NB * NH * 2;
    ushort* h1a   = (ushort*)ws;                 ws += (size_t)NB * NH * 2;
    ushort* h1b   = (ushort*)ws;                 ws += (size_t)NB * NH * 2;
    ushort* dec1b = (ushort*)ws;                 ws += (size_t)NB * NDEC * 2;

    const ushort* wih0 = wbf;
    const ushort* whh0 = wbf + 262144;
    const ushort* wih1 = wbf + 524288;
    const ushort* whh1 = wbf + 786432;
    const ushort* wd1  = wbf + 1048576;
    const ushort* wd2  = wbf + 1114112;

    convert_weights<<<1024, 256, 0, stream>>>(w_ih0, w_hh0, w_ih1, w_hh1, w_d1, w_d2,
                                              b_ih0, b_hh0, b_ih1, b_hh1,
                                              wbf, bsum0, bsum1);
    pool_kernel<<<NB * NSEG, 128, 0, stream>>>(inputs, embed, masks, xpool, xf);

    const dim3 blk(256);
    const dim3 gH (NH   / 64, NB / 64);   // (8,16)
    const dim3 gD1(NDEC / 64, NB / 64);   // (2,16)
    const dim3 gD2(ND   / 64, NB / 64);   // (8,16)

    // RNN scan over past = [3, 2, 0]; h starts at zero (K1=0 on step 0).
    mfma_gemm<true,false,true><<<gH, blk, 0, stream>>>(
        xpool + 3 * ND, NSEG * ND, nullptr, 0, wih0, ND, nullptr, 0,
        bsum0, nullptr, h0a, NH, ND, 0);
    mfma_gemm<true,false,true><<<gH, blk, 0, stream>>>(
        h0a, NH, nullptr, 0, wih1, NH, nullptr, 0,
        bsum1, nullptr, h1a, NH, NH, 0);
    mfma_gemm<true,false,true><<<gH, blk, 0, stream>>>(
        xpool + 2 * ND, NSEG * ND, h0a, NH, wih0, ND, whh0, NH,
        bsum0, nullptr, h0b, NH, ND, NH);
    mfma_gemm<true,false,true><<<gH, blk, 0, stream>>>(
        h0b, NH, h1a, NH, wih1, NH, whh1, NH,
        bsum1, nullptr, h1b, NH, NH, NH);
    mfma_gemm<true,false,true><<<gH, blk, 0, stream>>>(
        xpool + 0 * ND, NSEG * ND, h0b, NH, wih0, ND, whh0, NH,
        bsum0, nullptr, h0a, NH, ND, NH);
    mfma_gemm<true,true,true><<<gH, blk, 0, stream>>>(
        h0a, NH, h1b, NH, wih1, NH, whh1, NH,
        bsum1, lasth, h1a, NH, NH, NH);           // fp32 last_h -> d_out, bf16 -> h1a

    // decoder
    mfma_gemm<true,false,true><<<gD1, blk, 0, stream>>>(
        h1a, NH, nullptr, 0, wd1, NH, nullptr, 0,
        b_d1, nullptr, dec1b, NDEC, NH, 0);
    mfma_gemm<false,true,false><<<gD2, blk, 0, stream>>>(
        dec1b, NDEC, nullptr, 0, wd2, NDEC, nullptr, 0,
        b_d2, xf_hat, nullptr, ND, NDEC, 0);
}

// Round 3
// 149.720 us; speedup vs baseline: 3.1127x; 1.5860x over previous
//
#include <hip/hip_runtime.h>
#include <hip/hip_bf16.h>

// B=1024, M=4 segments, L=100 tokens, D=512, V=50000, H=512, DEC_HID=128
constexpr int NB   = 1024;
constexpr int NSEG = 4;
constexpr int LSEQ = 100;
constexpr int ND   = 512;
constexpr int NH   = 512;
constexpr int NDEC = 128;
constexpr size_t TBL_ELEMS = (size_t)50000 * ND;   // 25.6M floats

typedef __attribute__((ext_vector_type(8))) short bf16x8;
typedef __attribute__((ext_vector_type(4))) float f32x4;
typedef __attribute__((ext_vector_type(8))) unsigned short u16x8;

__device__ __forceinline__ ushort f2bf(float f) {
    union { float f; unsigned u; } v; v.f = f;
    unsigned r = (v.u + 0x7fffu + ((v.u >> 16) & 1u)) >> 16;   // RNE
    return (ushort)r;
}
__device__ __forceinline__ float bf2f(ushort u) {
    return __uint_as_float((unsigned)u << 16);
}

// global -> LDS direct copy, 16 B per lane. LDS dest wave-uniform base;
// lane i lands at base + i*16. Global src is per-lane (fragment-ordered).
#define GLOAD_LDS16(gp, lp)                                                     \
    __builtin_amdgcn_global_load_lds(                                           \
        (const __attribute__((address_space(1))) unsigned int*)(gp),            \
        (__attribute__((address_space(3))) unsigned int*)(lp), 16, 0, 0)

#define VMW(N) asm volatile("s_waitcnt vmcnt(" #N ")" ::: "memory")
#define RBAR() do { __builtin_amdgcn_s_barrier();                               \
                    __builtin_amdgcn_sched_barrier(0); } while (0)

// ---------------------------------------------------------------------------
// One-shot conversion: embed table fp32->bf16 (optional), 6 weight matrices
// fp32->bf16, RNN bias pairs pre-summed.
// ---------------------------------------------------------------------------
__global__ __launch_bounds__(256)
void convert_all(const float* __restrict__ table,
                 const float* __restrict__ w_ih0, const float* __restrict__ w_hh0,
                 const float* __restrict__ w_ih1, const float* __restrict__ w_hh1,
                 const float* __restrict__ w_d1,  const float* __restrict__ w_d2,
                 const float* __restrict__ b_ih0, const float* __restrict__ b_hh0,
                 const float* __restrict__ b_ih1, const float* __restrict__ b_hh1,
                 ushort* __restrict__ tbf, ushort* __restrict__ wbf,
                 float* __restrict__ bsum0, float* __restrict__ bsum1,
                 int doTable)
{
    const size_t stride = (size_t)gridDim.x * blockDim.x;
    const size_t gid    = (size_t)blockIdx.x * blockDim.x + threadIdx.x;

    if (doTable) {
        const size_t nvec = TBL_ELEMS / 8;
        for (size_t i = gid; i < nvec; i += stride) {
            const float4 a = ((const float4*)table)[2 * i];
            const float4 b = ((const float4*)table)[2 * i + 1];
            u16x8 o;
            o[0] = f2bf(a.x); o[1] = f2bf(a.y); o[2] = f2bf(a.z); o[3] = f2bf(a.w);
            o[4] = f2bf(b.x); o[5] = f2bf(b.y); o[6] = f2bf(b.z); o[7] = f2bf(b.w);
            ((u16x8*)tbf)[i] = o;
        }
    }
    constexpr int N0 = 512 * 512, ND2 = 128 * 512;
    constexpr int TOT = 4 * N0 + 2 * ND2 + 1024;
    for (size_t i = gid; i < TOT; i += stride) {
        if (i < 4 * (size_t)N0) {
            const float* src = (i < N0) ? w_ih0 : (i < 2*(size_t)N0) ? w_hh0
                             : (i < 3*(size_t)N0) ? w_ih1 : w_hh1;
            wbf[i] = f2bf(src[i & (N0 - 1)]);
        } else if (i < 4 * (size_t)N0 + ND2) {
            wbf[i] = f2bf(w_d1[i - 4 * (size_t)N0]);
        } else if (i < 4 * (size_t)N0 + 2 * ND2) {
            wbf[i] = f2bf(w_d2[i - 4 * (size_t)N0 - ND2]);
        } else {
            const int j = (int)(i - (4 * (size_t)N0 + 2 * ND2));
            if (j < 512) bsum0[j] = b_ih0[j] + b_hh0[j];
            else         bsum1[j - 512] = b_ih1[j - 512] + b_hh1[j - 512];
        }
    }
}

// ---------------------------------------------------------------------------
// Pooling: one wave per (b,m). Compact non-pad tokens via ballot, then gather
// embed rows with 8 loads in flight per lane (16 B each). BF selects bf16 vs
// fp32 table. m==1 -> fp32 x_future into d_out; else bf16 mask-scaled xpool.
// ---------------------------------------------------------------------------
template<bool BF>
__global__ __launch_bounds__(64)
void pool_kernel(const int* __restrict__ toks, const void* __restrict__ tbl,
                 const float* __restrict__ masks,
                 ushort* __restrict__ xpool, float* __restrict__ xfut)
{
    const int bm = blockIdx.x, m = bm & 3, lane = threadIdx.x;
    __shared__ int sidx[LSEQ];
    int cnt = 0;
    {
        const int t0 = toks[(size_t)bm * LSEQ + lane];
        const unsigned long long m0 = __ballot(t0 != 0);
        const int p0 = __popcll(m0 & ((1ull << lane) - 1ull));
        if (t0 != 0) sidx[p0] = t0;
        cnt = __popcll(m0);
        const int t1 = (lane < LSEQ - 64) ? toks[(size_t)bm * LSEQ + 64 + lane] : 0;
        const unsigned long long m1 = __ballot(t1 != 0);
        const int p1 = __popcll(m1 & ((1ull << lane) - 1ull));
        if (t1 != 0) sidx[cnt + p1] = t1;
        cnt += __popcll(m1);
    }
    __syncthreads();

    const int d = lane * 8;
    float acc[8] = {};
    int j = 0;
    if constexpr (BF) {
        const ushort* tb = (const ushort*)tbl;
        for (; j + 8 <= cnt; j += 8) {
            u16x8 v[8];
            #pragma unroll
            for (int u = 0; u < 8; ++u)
                v[u] = *(const u16x8*)&tb[(size_t)sidx[j + u] * ND + d];
            #pragma unroll
            for (int u = 0; u < 8; ++u)
                #pragma unroll
                for (int e = 0; e < 8; ++e) acc[e] += bf2f(v[u][e]);
        }
        for (; j < cnt; ++j) {
            const u16x8 v = *(const u16x8*)&tb[(size_t)sidx[j] * ND + d];
            #pragma unroll
            for (int e = 0; e < 8; ++e) acc[e] += bf2f(v[e]);
        }
    } else {
        const float* tb = (const float*)tbl;
        for (; j + 4 <= cnt; j += 4) {
            float4 v[4][2];
            #pragma unroll
            for (int u = 0; u < 4; ++u) {
                v[u][0] = *(const float4*)&tb[(size_t)sidx[j + u] * ND + d];
                v[u][1] = *(const float4*)&tb[(size_t)sidx[j + u] * ND + d + 4];
            }
            #pragma unroll
            for (int u = 0; u < 4; ++u) {
                acc[0] += v[u][0].x; acc[1] += v[u][0].y;
                acc[2] += v[u][0].z; acc[3] += v[u][0].w;
                acc[4] += v[u][1].x; acc[5] += v[u][1].y;
                acc[6] += v[u][1].z; acc[7] += v[u][1].w;
            }
        }
        for (; j < cnt; ++j) {
            const float4 a = *(const float4*)&tb[(size_t)sidx[j] * ND + d];
            const float4 b = *(const float4*)&tb[(size_t)sidx[j] * ND + d + 4];
            acc[0] += a.x; acc[1] += a.y; acc[2] += a.z; acc[3] += a.w;
            acc[4] += b.x; acc[5] += b.y; acc[6] += b.z; acc[7] += b.w;
        }
    }

    const float inv = 1.0f / (float)(cnt > 0 ? cnt : 1);
    if (m == 1) {
        float* dst = &xfut[(size_t)(bm >> 2) * ND + d];
        float4 o0 = {acc[0]*inv, acc[1]*inv, acc[2]*inv, acc[3]*inv};
        float4 o1 = {acc[4]*inv, acc[5]*inv, acc[6]*inv, acc[7]*inv};
        *(float4*)dst = o0; *(float4*)(dst + 4) = o1;
    } else {
        const float sc = masks[bm] * inv;      // mask is exactly 0.0 or 1.0
        u16x8 o;
        #pragma unroll
        for (int e = 0; e < 8; ++e) o[e] = f2bf(acc[e] * sc);
        *(u16x8*)&xpool[(size_t)bm * ND + d] = o;
    }
}

// ---------------------------------------------------------------------------
// bf16 MFMA GEMM, pipelined: C = act( [A0, A1] @ [W0, W1]^T + bias )
// 64x64 tile, BK=64, 256 threads = 4 waves (2x2 of 32x32 quadrants).
// 4-slot LDS pipeline, prefetch depth 3, counted vmcnt(12) + raw s_barrier
// (never drains the staging queue in the main loop). Peeled 3-step tail.
// Staging via global_load_lds(16B) with fragment-ordered per-lane global
// addresses -> lane-linear LDS, conflict-free ds_read_b128.
// All dims are multiples of the tile sizes; K0 (and K1) multiples of 64.
// ---------------------------------------------------------------------------
template<bool RELU, bool WF32, bool WBF>
__global__ __launch_bounds__(256)
void mfma_gemm(const ushort* __restrict__ A0, int lda0,
               const ushort* __restrict__ A1, int lda1,
               const ushort* __restrict__ W0, int ldw0,
               const ushort* __restrict__ W1, int ldw1,
               const float* __restrict__ bias,
               float* __restrict__ Cf, ushort* __restrict__ Cb, int ldc,
               int K0, int K1)
{
    __shared__ ushort SB[4][8192];    // 4 slots x (A 8KB | W 8KB)
    const int tid  = threadIdx.x;
    const int lane = tid & 63;
    const int wid  = tid >> 6;        // 0..3
    const int l15  = lane & 15;
    const int sl   = lane >> 4;       // k-chunk slot within 32-k group
    const int wr   = wid >> 1;        // quadrant row (0/1)
    const int wc   = wid & 1;         // quadrant col (0/1)
    const int row0 = blockIdx.y * 64;
    const int col0 = blockIdx.x * 64;
    const int nt   = (K0 + K1) >> 6;  // K-steps of 64

    f32x4 acc[2][2] = {};

    auto STAGE = [&](int t) {
        if (t >= nt) return;
        const int kg   = t * 64;
        const int ph   = (kg >= K0);
        const int koff = ph ? kg - K0 : kg;
        const ushort* Ap = ph ? A1 : A0;
        const int     la = ph ? lda1 : lda0;
        const ushort* Wp = ph ? W1 : W0;
        const int     lw = ph ? ldw1 : ldw0;
        ushort* dst = &SB[t & 3][0];
        // wave wid stages its 16-row block (fb == wid) for both A and W,
        // two 32-k sub-groups each (4 x 1KB chunks per wave per step).
        const ushort* ga = Ap + (size_t)(row0 + wid * 16 + l15) * la + koff + sl * 8;
        GLOAD_LDS16(ga,      dst + (wid * 2 + 0) * 512);
        GLOAD_LDS16(ga + 32, dst + (wid * 2 + 1) * 512);
        const ushort* gw = Wp + (size_t)(col0 + wid * 16 + l15) * lw + koff + sl * 8;
        GLOAD_LDS16(gw,      dst + 4096 + (wid * 2 + 0) * 512);
        GLOAD_LDS16(gw + 32, dst + 4096 + (wid * 2 + 1) * 512);
    };

    auto COMPUTE = [&](int t) {
        const ushort* base = &SB[t & 3][0];
        #pragma unroll
        for (int ks = 0; ks < 2; ++ks) {
            const bf16x8 a0 = *(const bf16x8*)&base[((wr*2 + 0)*2 + ks)*512 + lane*8];
            const bf16x8 a1 = *(const bf16x8*)&base[((wr*2 + 1)*2 + ks)*512 + lane*8];
            const bf16x8 b0 = *(const bf16x8*)&base[4096 + ((wc*2 + 0)*2 + ks)*512 + lane*8];
            const bf16x8 b1 = *(const bf16x8*)&base[4096 + ((wc*2 + 1)*2 + ks)*512 + lane*8];
            acc[0][0] = __builtin_amdgcn_mfma_f32_16x16x32_bf16(a0, b0, acc[0][0], 0, 0, 0);
            acc[0][1] = __builtin_amdgcn_mfma_f32_16x16x32_bf16(a0, b1, acc[0][1], 0, 0, 0);
            acc[1][0] = __builtin_amdgcn_mfma_f32_16x16x32_bf16(a1, b0, acc[1][0], 0, 0, 0);
            acc[1][1] = __builtin_amdgcn_mfma_f32_16x16x32_bf16(a1, b1, acc[1][1], 0, 0, 0);
        }
    };

    STAGE(0); STAGE(1); STAGE(2);
    int t = 0;
    for (; t < nt - 3; ++t) {
        STAGE(t + 3);
        VMW(12); RBAR();          // step t's 4 loads (per wave) complete
        COMPUTE(t);
        RBAR();                   // WAR: next STAGE reuses slot t%4
    }
    if (nt >= 3) { VMW(8); RBAR(); COMPUTE(nt - 3); }
    if (nt >= 2) { VMW(4); RBAR(); COMPUTE(nt - 2); }
    VMW(0); RBAR(); COMPUTE(nt - 1);

    #pragma unroll
    for (int fi = 0; fi < 2; ++fi)
        #pragma unroll
        for (int fj = 0; fj < 2; ++fj) {
            const int r0 = row0 + wr * 32 + fi * 16 + sl * 4;
            const int c  = col0 + wc * 32 + fj * 16 + l15;
            const float bb = bias ? bias[c] : 0.0f;
            #pragma unroll
            for (int r = 0; r < 4; ++r) {
                float v = acc[fi][fj][r] + bb;
                if (RELU) v = fmaxf(v, 0.0f);
                if (WF32) Cf[(size_t)(r0 + r) * ldc + c] = v;
                if (WBF)  Cb[(size_t)(r0 + r) * ldc + c] = f2bf(v);
            }
        }
}

extern "C" void kernel_launch(void* const* d_in, const int* in_sizes, int n_in,
                              void* d_out, int out_size, void* d_ws, size_t ws_size,
                              hipStream_t stream)
{
    (void)in_sizes; (void)n_in; (void)out_size;
    const int*   inputs = (const int*)  d_in[0];
    const float* masks  = (const float*)d_in[1];
    const float* embed  = (const float*)d_in[2];
    const float* w_ih0  = (const float*)d_in[3];
    const float* w_hh0  = (const float*)d_in[4];
    const float* b_ih0  = (const float*)d_in[5];
    const float* b_hh0  = (const float*)d_in[6];
    const float* w_ih1  = (const float*)d_in[7];
    const float* w_hh1  = (const float*)d_in[8];
    const float* b_ih1  = (const float*)d_in[9];
    const float* b_hh1  = (const float*)d_in[10];
    const float* w_d1   = (const float*)d_in[11];
    const float* b_d1   = (const float*)d_in[12];
    const float* w_d2   = (const float*)d_in[13];
    const float* b_d2   = (const float*)d_in[14];

    float* out    = (float*)d_out;
    float* xf_hat = out;                          // (B, D)
    float* xf     = out + (size_t)NB * ND;        // (B, D)
    float* lasth  = out + 2 * (size_t)NB * ND;    // (B, H)

    // workspace carve (bf16 table only if it fits)
    const size_t tbl_bytes  = TBL_ELEMS * 2;                       // 51.2 MB
    const size_t rest_bytes = (size_t)1179648 * 2 + 4096
                            + (size_t)NB * NSEG * ND * 2
                            + 4 * (size_t)NB * NH * 2
                            + (size_t)NB * NDEC * 2;
    const bool bigws = ws_size >= tbl_bytes + rest_bytes + 1024;

    char* ws = (char*)d_ws;
    ushort* tbf = nullptr;
    if (bigws) { tbf = (ushort*)ws; ws += tbl_bytes; }
    ushort* wbf   = (ushort*)ws;  ws += (size_t)1179648 * 2;
    float*  bsum0 = (float*)ws;   ws += 2048;
    float*  bsum1 = (float*)ws;   ws += 2048;
    ushort* xpool = (ushort*)ws;  ws += (size_t)NB * NSEG * ND * 2;
    ushort* h0a   = (ushort*)ws;  ws += (size_t)NB * NH * 2;
    ushort* h0b   = (ushort*)ws;  ws += (size_t)NB * NH * 2;
    ushort* h1a   = (ushort*)ws;  ws += (size_t)NB * NH * 2;
    ushort* h1b   = (ushort*)ws;  ws += (size_t)NB * NH * 2;
    ushort* dec1b = (ushort*)ws;  ws += (size_t)NB * NDEC * 2;

    const ushort* wih0 = wbf;
    const ushort* whh0 = wbf + 262144;
    const ushort* wih1 = wbf + 524288;
    const ushort* whh1 = wbf + 786432;
    const ushort* wd1  = wbf + 1048576;
    const ushort* wd2  = wbf + 1114112;

    convert_all<<<2048, 256, 0, stream>>>(embed, w_ih0, w_hh0, w_ih1, w_hh1,
                                          w_d1, w_d2, b_ih0, b_hh0, b_ih1, b_hh1,
                                          tbf, wbf, bsum0, bsum1, bigws ? 1 : 0);
    if (bigws)
        pool_kernel<true ><<<NB * NSEG, 64, 0, stream>>>(inputs, tbf,   masks, xpool, xf);
    else
        pool_kernel<false><<<NB * NSEG, 64, 0, stream>>>(inputs, embed, masks, xpool, xf);

    const dim3 blk(256);
    const dim3 gH (NH   / 64, NB / 64);   // (8,16)
    const dim3 gD1(NDEC / 64, NB / 64);   // (2,16)
    const dim3 gD2(ND   / 64, NB / 64);   // (8,16)

    // RNN scan over past = [3, 2, 0]; h starts at zero (K1=0 on step 0).
    mfma_gemm<true,false,true><<<gH, blk, 0, stream>>>(
        xpool + 3 * ND, NSEG * ND, nullptr, 0, wih0, ND, nullptr, 0,
        bsum0, nullptr, h0a, NH, ND, 0);
    mfma_gemm<true,false,true><<<gH, blk, 0, stream>>>(
        h0a, NH, nullptr, 0, wih1, NH, nullptr, 0,
        bsum1, nullptr, h1a, NH, NH, 0);
    mfma_gemm<true,false,true><<<gH, blk, 0, stream>>>(
        xpool + 2 * ND, NSEG * ND, h0a, NH, wih0, ND, whh0, NH,
        bsum0, nullptr, h0b, NH, ND, NH);
    mfma_gemm<true,false,true><<<gH, blk, 0, stream>>>(
        h0b, NH, h1a, NH, wih1, NH, whh1, NH,
        bsum1, nullptr, h1b, NH, NH, NH);
    mfma_gemm<true,false,true><<<gH, blk, 0, stream>>>(
        xpool + 0 * ND, NSEG * ND, h0b, NH, wih0, ND, whh0, NH,
        bsum0, nullptr, h0a, NH, ND, NH);
    mfma_gemm<true,true,true><<<gH, blk, 0, stream>>>(
        h0a, NH, h1b, NH, wih1, NH, whh1, NH,
        bsum1, lasth, h1a, NH, NH, NH);           // fp32 last_h -> d_out, bf16 -> h1a

    // decoder
    mfma_gemm<true,false,true><<<gD1, blk, 0, stream>>>(
        h1a, NH, nullptr, 0, wd1, NH, nullptr, 0,
        b_d1, nullptr, dec1b, NDEC, NH, 0);
    mfma_gemm<false,true,false><<<gD2, blk, 0, stream>>>(
        dec1b, NDEC, nullptr, 0, wd2, NDEC, nullptr, 0,
        b_d2, xf_hat, nullptr, ND, NDEC, 0);
}

// Round 4
// 116.166 us; speedup vs baseline: 4.0118x; 1.2888x over previous
//
#include <hip/hip_runtime.h>
#include <hip/hip_bf16.h>

// B=1024, M=4 segments, L=100 tokens, D=512, V=50000, H=512, DEC_HID=128
constexpr int NB   = 1024;
constexpr int NSEG = 4;
constexpr int LSEQ = 100;
constexpr int ND   = 512;
constexpr int NH   = 512;
constexpr int NDEC = 128;
constexpr size_t TBL_ELEMS = (size_t)50000 * ND;   // 25.6M elems

typedef __attribute__((ext_vector_type(8))) short bf16x8;
typedef __attribute__((ext_vector_type(4))) float f32x4;
typedef __attribute__((ext_vector_type(2))) float f32x2;
typedef __attribute__((ext_vector_type(8))) unsigned short u16x8;

__device__ __forceinline__ ushort f2bf(float f) {
    union { float f; unsigned u; } v; v.f = f;
    unsigned r = (v.u + 0x7fffu + ((v.u >> 16) & 1u)) >> 16;   // RNE
    return (ushort)r;
}
__device__ __forceinline__ float bf2f(ushort u) {
    return __uint_as_float((unsigned)u << 16);
}

// global -> LDS direct copy, 16 B per lane. LDS dest wave-uniform base;
// lane i lands at base + i*16. Global src is per-lane (fragment-ordered).
#define GLOAD_LDS16(gp, lp)                                                     \
    __builtin_amdgcn_global_load_lds(                                           \
        (const __attribute__((address_space(1))) unsigned int*)(gp),            \
        (__attribute__((address_space(3))) unsigned int*)(lp), 16, 0, 0)

#define VMW(N) asm volatile("s_waitcnt vmcnt(" #N ")" ::: "memory")
#define RBAR() do { __builtin_amdgcn_s_barrier();                               \
                    __builtin_amdgcn_sched_barrier(0); } while (0)

// ---------------------------------------------------------------------------
// One-shot conversion: embed table fp32->fp8 e4m3 (hardware cvt, RNE),
// 6 weight matrices fp32->bf16, RNN bias pairs pre-summed.
// ---------------------------------------------------------------------------
__global__ __launch_bounds__(256)
void convert_all(const float* __restrict__ table,
                 const float* __restrict__ w_ih0, const float* __restrict__ w_hh0,
                 const float* __restrict__ w_ih1, const float* __restrict__ w_hh1,
                 const float* __restrict__ w_d1,  const float* __restrict__ w_d2,
                 const float* __restrict__ b_ih0, const float* __restrict__ b_hh0,
                 const float* __restrict__ b_ih1, const float* __restrict__ b_hh1,
                 unsigned* __restrict__ tb8, ushort* __restrict__ wbf,
                 float* __restrict__ bsum0, float* __restrict__ bsum1,
                 int doTable)
{
    const size_t stride = (size_t)gridDim.x * blockDim.x;
    const size_t gid    = (size_t)blockIdx.x * blockDim.x + threadIdx.x;

    if (doTable) {
        const size_t nvec = TBL_ELEMS / 8;     // 8 floats -> 8 fp8 bytes
        for (size_t i = gid; i < nvec; i += stride) {
            const float4 a = ((const float4*)table)[2 * i];
            const float4 b = ((const float4*)table)[2 * i + 1];
            unsigned w0 = __builtin_amdgcn_cvt_pk_fp8_f32(a.x, a.y, 0, false);
            w0          = __builtin_amdgcn_cvt_pk_fp8_f32(a.z, a.w, w0, true);
            unsigned w1 = __builtin_amdgcn_cvt_pk_fp8_f32(b.x, b.y, 0, false);
            w1          = __builtin_amdgcn_cvt_pk_fp8_f32(b.z, b.w, w1, true);
            uint2 o; o.x = w0; o.y = w1;
            ((uint2*)tb8)[i] = o;
        }
    }
    constexpr int N0 = 512 * 512, ND2 = 128 * 512;
    constexpr int TOT = 4 * N0 + 2 * ND2 + 1024;
    for (size_t i = gid; i < TOT; i += stride) {
        if (i < 4 * (size_t)N0) {
            const float* src = (i < N0) ? w_ih0 : (i < 2*(size_t)N0) ? w_hh0
                             : (i < 3*(size_t)N0) ? w_ih1 : w_hh1;
            wbf[i] = f2bf(src[i & (N0 - 1)]);
        } else if (i < 4 * (size_t)N0 + ND2) {
            wbf[i] = f2bf(w_d1[i - 4 * (size_t)N0]);
        } else if (i < 4 * (size_t)N0 + 2 * ND2) {
            wbf[i] = f2bf(w_d2[i - 4 * (size_t)N0 - ND2]);
        } else {
            const int j = (int)(i - (4 * (size_t)N0 + 2 * ND2));
            if (j < 512) bsum0[j] = b_ih0[j] + b_hh0[j];
            else         bsum1[j - 512] = b_ih1[j - 512] + b_hh1[j - 512];
        }
    }
}

// ---------------------------------------------------------------------------
// Pooling: one wave per (b,m). Compact non-pad tokens via ballot, then gather
// embed rows with 8 rows in flight per lane. FP8 path: 8 B/lane/row (8 fp8),
// hardware v_cvt_pk_f32_fp8 unpack. Fallback fp32 path if ws too small.
// m==1 -> fp32 x_future into d_out; else bf16 mask-scaled xpool.
// ---------------------------------------------------------------------------
template<bool FP8>
__global__ __launch_bounds__(64)
void pool_kernel(const int* __restrict__ toks, const void* __restrict__ tbl,
                 const float* __restrict__ masks,
                 ushort* __restrict__ xpool, float* __restrict__ xfut)
{
    const int bm = blockIdx.x, m = bm & 3, lane = threadIdx.x;
    __shared__ int sidx[LSEQ];
    int cnt = 0;
    {
        const int t0 = toks[(size_t)bm * LSEQ + lane];
        const unsigned long long m0 = __ballot(t0 != 0);
        const int p0 = __popcll(m0 & ((1ull << lane) - 1ull));
        if (t0 != 0) sidx[p0] = t0;
        cnt = __popcll(m0);
        const int t1 = (lane < LSEQ - 64) ? toks[(size_t)bm * LSEQ + 64 + lane] : 0;
        const unsigned long long m1 = __ballot(t1 != 0);
        const int p1 = __popcll(m1 & ((1ull << lane) - 1ull));
        if (t1 != 0) sidx[cnt + p1] = t1;
        cnt += __popcll(m1);
    }
    __syncthreads();

    float acc[8] = {};
    int j = 0;
    if constexpr (FP8) {
        const unsigned char* tb = (const unsigned char*)tbl;
        const size_t off = (size_t)lane * 8;               // byte offset in row
        for (; j + 8 <= cnt; j += 8) {
            uint2 v[8];
            #pragma unroll
            for (int u = 0; u < 8; ++u)
                v[u] = *(const uint2*)&tb[(size_t)sidx[j + u] * ND + off];
            #pragma unroll
            for (int u = 0; u < 8; ++u) {
                const f32x2 p0 = __builtin_amdgcn_cvt_pk_f32_fp8(v[u].x, false);
                const f32x2 p1 = __builtin_amdgcn_cvt_pk_f32_fp8(v[u].x, true);
                const f32x2 p2 = __builtin_amdgcn_cvt_pk_f32_fp8(v[u].y, false);
                const f32x2 p3 = __builtin_amdgcn_cvt_pk_f32_fp8(v[u].y, true);
                acc[0] += p0[0]; acc[1] += p0[1]; acc[2] += p1[0]; acc[3] += p1[1];
                acc[4] += p2[0]; acc[5] += p2[1]; acc[6] += p3[0]; acc[7] += p3[1];
            }
        }
        for (; j < cnt; ++j) {
            const uint2 v = *(const uint2*)&tb[(size_t)sidx[j] * ND + off];
            const f32x2 p0 = __builtin_amdgcn_cvt_pk_f32_fp8(v.x, false);
            const f32x2 p1 = __builtin_amdgcn_cvt_pk_f32_fp8(v.x, true);
            const f32x2 p2 = __builtin_amdgcn_cvt_pk_f32_fp8(v.y, false);
            const f32x2 p3 = __builtin_amdgcn_cvt_pk_f32_fp8(v.y, true);
            acc[0] += p0[0]; acc[1] += p0[1]; acc[2] += p1[0]; acc[3] += p1[1];
            acc[4] += p2[0]; acc[5] += p2[1]; acc[6] += p3[0]; acc[7] += p3[1];
        }
    } else {
        const float* tb = (const float*)tbl;
        const int d = lane * 8;
        for (; j + 4 <= cnt; j += 4) {
            float4 v[4][2];
            #pragma unroll
            for (int u = 0; u < 4; ++u) {
                v[u][0] = *(const float4*)&tb[(size_t)sidx[j + u] * ND + d];
                v[u][1] = *(const float4*)&tb[(size_t)sidx[j + u] * ND + d + 4];
            }
            #pragma unroll
            for (int u = 0; u < 4; ++u) {
                acc[0] += v[u][0].x; acc[1] += v[u][0].y;
                acc[2] += v[u][0].z; acc[3] += v[u][0].w;
                acc[4] += v[u][1].x; acc[5] += v[u][1].y;
                acc[6] += v[u][1].z; acc[7] += v[u][1].w;
            }
        }
        for (; j < cnt; ++j) {
            const float4 a = *(const float4*)&tb[(size_t)sidx[j] * ND + d];
            const float4 b = *(const float4*)&tb[(size_t)sidx[j] * ND + d + 4];
            acc[0] += a.x; acc[1] += a.y; acc[2] += a.z; acc[3] += a.w;
            acc[4] += b.x; acc[5] += b.y; acc[6] += b.z; acc[7] += b.w;
        }
    }

    const float inv = 1.0f / (float)(cnt > 0 ? cnt : 1);
    const int d = lane * 8;
    if (m == 1) {
        float* dst = &xfut[(size_t)(bm >> 2) * ND + d];
        float4 o0 = {acc[0]*inv, acc[1]*inv, acc[2]*inv, acc[3]*inv};
        float4 o1 = {acc[4]*inv, acc[5]*inv, acc[6]*inv, acc[7]*inv};
        *(float4*)dst = o0; *(float4*)(dst + 4) = o1;
    } else {
        const float sc = masks[bm] * inv;      // mask is exactly 0.0 or 1.0
        u16x8 o;
        #pragma unroll
        for (int e = 0; e < 8; ++e) o[e] = f2bf(acc[e] * sc);
        *(u16x8*)&xpool[(size_t)bm * ND + d] = o;
    }
}

// ---------------------------------------------------------------------------
// bf16 MFMA GEMM, pipelined: C = act( [A0, A1] @ [W0, W1]^T + bias )
// 64x64 tile, BK=64, 256 threads = 4 waves (2x2 of 32x32 quadrants).
// 4-slot LDS pipeline, prefetch depth 3, counted vmcnt(12) + raw s_barrier.
// 1D grid with chunked XCD swizzle: XCD k owns a contiguous row-tile range
// (all cols) -> A fetched once per XCD region instead of once per col-tile.
// All dims multiples of tile sizes; K0 (and K1) multiples of 64; nwg % 8 == 0.
// ---------------------------------------------------------------------------
template<bool RELU, bool WF32, bool WBF>
__global__ __launch_bounds__(256)
void mfma_gemm(const ushort* __restrict__ A0, int lda0,
               const ushort* __restrict__ A1, int lda1,
               const ushort* __restrict__ W0, int ldw0,
               const ushort* __restrict__ W1, int ldw1,
               const float* __restrict__ bias,
               float* __restrict__ Cf, ushort* __restrict__ Cb, int ldc,
               int K0, int K1, int gx)
{
    __shared__ ushort SB[4][8192];    // 4 slots x (A 8KB | W 8KB)
    const int tid  = threadIdx.x;
    const int lane = tid & 63;
    const int wid  = tid >> 6;        // 0..3
    const int l15  = lane & 15;
    const int sl   = lane >> 4;       // k-chunk slot within 32-k group
    const int wr   = wid >> 1;        // quadrant row (0/1)
    const int wc   = wid & 1;         // quadrant col (0/1)

    // chunked XCD swizzle (blockIdx round-robins XCDs by id & 7)
    const int per  = gridDim.x >> 3;
    const int tile = (blockIdx.x & 7) * per + (blockIdx.x >> 3);  // row-major id
    const int row0 = (tile / gx) * 64;
    const int col0 = (tile % gx) * 64;
    const int nt   = (K0 + K1) >> 6;  // K-steps of 64

    f32x4 acc[2][2] = {};

    auto STAGE = [&](int t) {
        if (t >= nt) return;
        const int kg   = t * 64;
        const int ph   = (kg >= K0);
        const int koff = ph ? kg - K0 : kg;
        const ushort* Ap = ph ? A1 : A0;
        const int     la = ph ? lda1 : lda0;
        const ushort* Wp = ph ? W1 : W0;
        const int     lw = ph ? ldw1 : ldw0;
        ushort* dst = &SB[t & 3][0];
        const ushort* ga = Ap + (size_t)(row0 + wid * 16 + l15) * la + koff + sl * 8;
        GLOAD_LDS16(ga,      dst + (wid * 2 + 0) * 512);
        GLOAD_LDS16(ga + 32, dst + (wid * 2 + 1) * 512);
        const ushort* gw = Wp + (size_t)(col0 + wid * 16 + l15) * lw + koff + sl * 8;
        GLOAD_LDS16(gw,      dst + 4096 + (wid * 2 + 0) * 512);
        GLOAD_LDS16(gw + 32, dst + 4096 + (wid * 2 + 1) * 512);
    };

    auto COMPUTE = [&](int t) {
        const ushort* base = &SB[t & 3][0];
        #pragma unroll
        for (int ks = 0; ks < 2; ++ks) {
            const bf16x8 a0 = *(const bf16x8*)&base[((wr*2 + 0)*2 + ks)*512 + lane*8];
            const bf16x8 a1 = *(const bf16x8*)&base[((wr*2 + 1)*2 + ks)*512 + lane*8];
            const bf16x8 b0 = *(const bf16x8*)&base[4096 + ((wc*2 + 0)*2 + ks)*512 + lane*8];
            const bf16x8 b1 = *(const bf16x8*)&base[4096 + ((wc*2 + 1)*2 + ks)*512 + lane*8];
            acc[0][0] = __builtin_amdgcn_mfma_f32_16x16x32_bf16(a0, b0, acc[0][0], 0, 0, 0);
            acc[0][1] = __builtin_amdgcn_mfma_f32_16x16x32_bf16(a0, b1, acc[0][1], 0, 0, 0);
            acc[1][0] = __builtin_amdgcn_mfma_f32_16x16x32_bf16(a1, b0, acc[1][0], 0, 0, 0);
            acc[1][1] = __builtin_amdgcn_mfma_f32_16x16x32_bf16(a1, b1, acc[1][1], 0, 0, 0);
        }
    };

    STAGE(0); STAGE(1); STAGE(2);
    int t = 0;
    for (; t < nt - 3; ++t) {
        STAGE(t + 3);
        VMW(12); RBAR();          // step t's loads complete
        COMPUTE(t);
        RBAR();                   // WAR: next STAGE reuses slot t%4
    }
    if (nt >= 3) { VMW(8); RBAR(); COMPUTE(nt - 3); }
    if (nt >= 2) { VMW(4); RBAR(); COMPUTE(nt - 2); }
    VMW(0); RBAR(); COMPUTE(nt - 1);

    #pragma unroll
    for (int fi = 0; fi < 2; ++fi)
        #pragma unroll
        for (int fj = 0; fj < 2; ++fj) {
            const int r0 = row0 + wr * 32 + fi * 16 + sl * 4;
            const int c  = col0 + wc * 32 + fj * 16 + l15;
            const float bb = bias ? bias[c] : 0.0f;
            #pragma unroll
            for (int r = 0; r < 4; ++r) {
                float v = acc[fi][fj][r] + bb;
                if (RELU) v = fmaxf(v, 0.0f);
                if (WF32) Cf[(size_t)(r0 + r) * ldc + c] = v;
                if (WBF)  Cb[(size_t)(r0 + r) * ldc + c] = f2bf(v);
            }
        }
}

extern "C" void kernel_launch(void* const* d_in, const int* in_sizes, int n_in,
                              void* d_out, int out_size, void* d_ws, size_t ws_size,
                              hipStream_t stream)
{
    (void)in_sizes; (void)n_in; (void)out_size;
    const int*   inputs = (const int*)  d_in[0];
    const float* masks  = (const float*)d_in[1];
    const float* embed  = (const float*)d_in[2];
    const float* w_ih0  = (const float*)d_in[3];
    const float* w_hh0  = (const float*)d_in[4];
    const float* b_ih0  = (const float*)d_in[5];
    const float* b_hh0  = (const float*)d_in[6];
    const float* w_ih1  = (const float*)d_in[7];
    const float* w_hh1  = (const float*)d_in[8];
    const float* b_ih1  = (const float*)d_in[9];
    const float* b_hh1  = (const float*)d_in[10];
    const float* w_d1   = (const float*)d_in[11];
    const float* b_d1   = (const float*)d_in[12];
    const float* w_d2   = (const float*)d_in[13];
    const float* b_d2   = (const float*)d_in[14];

    float* out    = (float*)d_out;
    float* xf_hat = out;                          // (B, D)
    float* xf     = out + (size_t)NB * ND;        // (B, D)
    float* lasth  = out + 2 * (size_t)NB * ND;    // (B, H)

    // workspace carve (fp8 table only if it fits)
    const size_t tbl_bytes  = TBL_ELEMS;                            // 25.6 MB
    const size_t rest_bytes = (size_t)1179648 * 2 + 4096
                            + (size_t)NB * NSEG * ND * 2
                            + 4 * (size_t)NB * NH * 2
                            + (size_t)NB * NDEC * 2;
    const bool bigws = ws_size >= tbl_bytes + rest_bytes + 1024;

    char* ws = (char*)d_ws;
    unsigned* tb8 = nullptr;
    if (bigws) { tb8 = (unsigned*)ws; ws += tbl_bytes; }
    ushort* wbf   = (ushort*)ws;  ws += (size_t)1179648 * 2;
    float*  bsum0 = (float*)ws;   ws += 2048;
    float*  bsum1 = (float*)ws;   ws += 2048;
    ushort* xpool = (ushort*)ws;  ws += (size_t)NB * NSEG * ND * 2;
    ushort* h0a   = (ushort*)ws;  ws += (size_t)NB * NH * 2;
    ushort* h0b   = (ushort*)ws;  ws += (size_t)NB * NH * 2;
    ushort* h1a   = (ushort*)ws;  ws += (size_t)NB * NH * 2;
    ushort* h1b   = (ushort*)ws;  ws += (size_t)NB * NH * 2;
    ushort* dec1b = (ushort*)ws;  ws += (size_t)NB * NDEC * 2;

    const ushort* wih0 = wbf;
    const ushort* whh0 = wbf + 262144;
    const ushort* wih1 = wbf + 524288;
    const ushort* whh1 = wbf + 786432;
    const ushort* wd1  = wbf + 1048576;
    const ushort* wd2  = wbf + 1114112;

    convert_all<<<2048, 256, 0, stream>>>(embed, w_ih0, w_hh0, w_ih1, w_hh1,
                                          w_d1, w_d2, b_ih0, b_hh0, b_ih1, b_hh1,
                                          tb8, wbf, bsum0, bsum1, bigws ? 1 : 0);
    if (bigws)
        pool_kernel<true ><<<NB * NSEG, 64, 0, stream>>>(inputs, tb8,   masks, xpool, xf);
    else
        pool_kernel<false><<<NB * NSEG, 64, 0, stream>>>(inputs, embed, masks, xpool, xf);

    const dim3 blk(256);
    const int nH  = (NH / 64)   * (NB / 64);   // 128 blocks, gx=8
    const int nD1 = (NDEC / 64) * (NB / 64);   // 32 blocks,  gx=2
    const int nD2 = (ND / 64)   * (NB / 64);   // 128 blocks, gx=8

    // RNN scan over past = [3, 2, 0]; h starts at zero (K1=0 on step 0).
    mfma_gemm<true,false,true><<<nH, blk, 0, stream>>>(
        xpool + 3 * ND, NSEG * ND, nullptr, 0, wih0, ND, nullptr, 0,
        bsum0, nullptr, h0a, NH, ND, 0, 8);
    mfma_gemm<true,false,true><<<nH, blk, 0, stream>>>(
        h0a, NH, nullptr, 0, wih1, NH, nullptr, 0,
        bsum1, nullptr, h1a, NH, NH, 0, 8);
    mfma_gemm<true,false,true><<<nH, blk, 0, stream>>>(
        xpool + 2 * ND, NSEG * ND, h0a, NH, wih0, ND, whh0, NH,
        bsum0, nullptr, h0b, NH, ND, NH, 8);
    mfma_gemm<true,false,true><<<nH, blk, 0, stream>>>(
        h0b, NH, h1a, NH, wih1, NH, whh1, NH,
        bsum1, nullptr, h1b, NH, NH, NH, 8);
    mfma_gemm<true,false,true><<<nH, blk, 0, stream>>>(
        xpool + 0 * ND, NSEG * ND, h0b, NH, wih0, ND, whh0, NH,
        bsum0, nullptr, h0a, NH, ND, NH, 8);
    mfma_gemm<true,true,true><<<nH, blk, 0, stream>>>(
        h0a, NH, h1b, NH, wih1, NH, whh1, NH,
        bsum1, lasth, h1a, NH, NH, NH, 8);        // fp32 last_h -> d_out, bf16 -> h1a

    // decoder
    mfma_gemm<true,false,true><<<nD1, blk, 0, stream>>>(
        h1a, NH, nullptr, 0, wd1, NH, nullptr, 0,
        b_d1, nullptr, dec1b, NDEC, NH, 0, 2);
    mfma_gemm<false,true,false><<<nD2, blk, 0, stream>>>(
        dec1b, NDEC, nullptr, 0, wd2, NDEC, nullptr, 0,
        b_d2, xf_hat, nullptr, ND, NDEC, 0, 8);
}